// Round 3
// baseline (4931.690 us; speedup 1.0000x reference)
//
#include <hip/hip_runtime.h>
#include <cstddef>

constexpr int IMG = 256;
constexpr int NPIX = 65536;

// ---------------------------------------------------------------------------
// Direct 3x3 conv, padding 1, NCHW. Tile = 32x8 pixels, 1 px/thread,
// 16 couts/block, CC=8 cin per LDS chunk, register-double-buffered staging.
// Weights: block-uniform compile-time offsets -> batched s_loads.
// SUMIN: staged input = in + in2 + cbias[c] (folds mdcn partial-reduce+bias
// into the fusion conv's staging).
// ---------------------------------------------------------------------------
template<int CIN, int WROW, bool LRELU, bool ACCUM, bool SUMIN>
__global__ __launch_bounds__(256) void conv3x3_k(
    const float* __restrict__ in, const float* __restrict__ in2,
    const float* __restrict__ cbias,
    const float* __restrict__ w, const float* __restrict__ bias,
    float* __restrict__ out, int cout)
{
  constexpr int CC  = 8;
  constexpr int HAL = 10 * 34;          // halo tile per cin: 340
  constexpr int TOT = CC * HAL;         // 2720
  constexpr int PRE = (TOT + 255) / 256;  // 11 staging loads / thread
  __shared__ float sIn[TOT];

  const int tid = threadIdx.x;
  const int ty0 = (blockIdx.x >> 3) << 3;   // 32 y-tiles of 8 rows
  const int tx0 = (blockIdx.x & 7) << 5;    // 8 x-tiles of 32 cols
  int co0 = blockIdx.y * 16;
  if (co0 + 16 > cout) co0 = cout - 16;     // tail: overlap-recompute, benign
  const int px = tid & 31, py = tid >> 5;

  // staging source indices are chunk-invariant: precompute once
  int  bidx[PRE];
  int  bcs[PRE];
  bool bval[PRE];
#pragma unroll
  for (int j = 0; j < PRE; ++j) {
    int i = tid + j * 256;
    int cs = i / HAL, r = i - cs * HAL;
    int ry = r / 34, rx = r - ry * 34;
    int gy = ty0 - 1 + ry, gx = tx0 - 1 + rx;
    bcs[j]  = cs;
    bval[j] = (i < TOT) && ((unsigned)gy < (unsigned)IMG) &&
              ((unsigned)gx < (unsigned)IMG);
    bidx[j] = cs * NPIX + gy * IMG + gx;
  }

  float pf[PRE];
  auto fetch = [&](int c0) {
#pragma unroll
    for (int j = 0; j < PRE; ++j) {
      float v = 0.f;
      if (bval[j]) {
        size_t gi = (size_t)c0 * NPIX + bidx[j];
        v = in[gi];
        if (SUMIN) v += in2[gi] + cbias[c0 + bcs[j]];
      }
      pf[j] = v;
    }
  };

  float acc[16];
#pragma unroll
  for (int i = 0; i < 16; ++i) acc[i] = 0.f;

  fetch(0);
  for (int c0 = 0; c0 < CIN; c0 += CC) {
    __syncthreads();
#pragma unroll
    for (int j = 0; j < PRE; ++j) {
      int i = tid + j * 256;
      if (i < TOT) sIn[i] = pf[j];
    }
    __syncthreads();
    if (c0 + CC < CIN) fetch(c0 + CC);   // overlap next staging with compute

    const float* wp = w + (size_t)co0 * WROW + c0 * 9;
#pragma unroll
    for (int cs = 0; cs < CC; ++cs) {
      float v[9];
#pragma unroll
      for (int dy = 0; dy < 3; ++dy)
#pragma unroll
        for (int dx = 0; dx < 3; ++dx)
          v[dy * 3 + dx] = sIn[cs * HAL + (py + dy) * 34 + px + dx];
#pragma unroll
      for (int co = 0; co < 16; ++co)
#pragma unroll
        for (int k = 0; k < 9; ++k)
          acc[co] = fmaf(wp[co * WROW + cs * 9 + k], v[k], acc[co]);
    }
  }

  const size_t pixo = (size_t)(ty0 + py) * IMG + tx0 + px;
#pragma unroll
  for (int co = 0; co < 16; ++co) {
    size_t oidx = (size_t)(co0 + co) * NPIX + pixo;
    if (ACCUM) {
      out[oidx] += acc[co];
    } else {
      float r = acc[co] + bias[co0 + co];
      if (LRELU) r = (r >= 0.f) ? r : 0.1f * r;
      out[oidx] = r;
    }
  }
}

// ---------------------------------------------------------------------------
// feat CHW -> per-group layout featG[g][pix][8]
// ---------------------------------------------------------------------------
__global__ __launch_bounds__(256) void featg_k(
    const float* __restrict__ in, float* __restrict__ out)
{
  int pix = blockIdx.x * 256 + threadIdx.x;
#pragma unroll
  for (int g = 0; g < 8; ++g) {
    float4 a, b;
    a.x = in[(size_t)(g * 8 + 0) * NPIX + pix];
    a.y = in[(size_t)(g * 8 + 1) * NPIX + pix];
    a.z = in[(size_t)(g * 8 + 2) * NPIX + pix];
    a.w = in[(size_t)(g * 8 + 3) * NPIX + pix];
    b.x = in[(size_t)(g * 8 + 4) * NPIX + pix];
    b.y = in[(size_t)(g * 8 + 5) * NPIX + pix];
    b.z = in[(size_t)(g * 8 + 6) * NPIX + pix];
    b.w = in[(size_t)(g * 8 + 7) * NPIX + pix];
    float* o = out + ((size_t)g * NPIX + pix) * 8;
    *reinterpret_cast<float4*>(o) = a;
    *reinterpret_cast<float4*>(o + 4) = b;
  }
}

// ---------------------------------------------------------------------------
// dcn weight transpose: wT[((g*9+k)*8 + c)*64 + o] = w[o*576 + g*72 + c*9 + k]
// ---------------------------------------------------------------------------
__global__ __launch_bounds__(256) void wtprep_k(
    const float* __restrict__ w, float* __restrict__ wT)
{
  int i = blockIdx.x * 256 + threadIdx.x;   // 36864 total
  int o = i & 63;
  int r = i >> 6;
  int c = r & 7;
  int gk = r >> 3;
  int k = gk % 9;
  int g = gk / 9;
  wT[i] = w[(size_t)o * 576 + g * 72 + c * 9 + k];
}

// ---------------------------------------------------------------------------
// MDCN sample + partial GEMM, software-pipelined taps.
// One thread = one pixel, 4 groups (blockIdx.y). Per group: batch-load the
// 27 offset/mask values (one latency window), then per tap issue the next
// tap's gathers before the current tap's 512-FMA block.
// ---------------------------------------------------------------------------
__global__ __launch_bounds__(256) void mdcn_sample_k(
    const float* __restrict__ featG, const float* __restrict__ o216,
    const float* __restrict__ flow, const float* __restrict__ wT,
    float* __restrict__ part0, float* __restrict__ part1)
{
  const int pix = blockIdx.x * 256 + threadIdx.x;
  const int h = pix >> 8, x = pix & 255;
  const float fy = flow[NPIX + pix];   // flow[:, ::-1]: even off-ch += flow[1]
  const float fx = flow[pix];

  float acc[64];
#pragma unroll
  for (int o = 0; o < 64; ++o) acc[o] = 0.f;

#pragma unroll 1
  for (int gg = 0; gg < 4; ++gg) {
    const int g = (blockIdx.y << 2) + gg;          // wave-uniform
    const float* fg = featG + (size_t)g * NPIX * 8;

    // batch the 27 raw offset/mask loads -> single latency window
    float raw[27];
#pragma unroll
    for (int k = 0; k < 9; ++k) {
      raw[3 * k + 0] = o216[(size_t)(g * 18 + 2 * k) * NPIX + pix];
      raw[3 * k + 1] = o216[(size_t)(g * 18 + 2 * k + 1) * NPIX + pix];
      raw[3 * k + 2] = o216[(size_t)(144 + g * 9 + k) * NPIX + pix];
    }

    float pw0, pw1, pw2, pw3;
    const float* pp00; const float* pp01; const float* pp10; const float* pp11;
    auto params = [&](int k) {
      float m = 1.f / (1.f + __expf(-raw[3 * k + 2]));
      float pyf = (float)h + (float)(k / 3 - 1) + 10.f * tanhf(raw[3 * k]) + fy;
      float pxf = (float)x + (float)(k % 3 - 1) + 10.f * tanhf(raw[3 * k + 1]) + fx;
      float y0f = floorf(pyf), x0f = floorf(pxf);
      float ly = pyf - y0f, lx = pxf - x0f;
      int y0 = (int)y0f, x0 = (int)x0f;
      int y1 = y0 + 1, x1 = x0 + 1;
      bool vy0 = (unsigned)y0 < (unsigned)IMG, vy1 = (unsigned)y1 < (unsigned)IMG;
      bool vx0 = (unsigned)x0 < (unsigned)IMG, vx1 = (unsigned)x1 < (unsigned)IMG;
      int y0c = min(max(y0, 0), IMG - 1), y1c = min(max(y1, 0), IMG - 1);
      int x0c = min(max(x0, 0), IMG - 1), x1c = min(max(x1, 0), IMG - 1);
      pw0 = (vy0 && vx0) ? (1.f - ly) * (1.f - lx) * m : 0.f;
      pw1 = (vy0 && vx1) ? (1.f - ly) * lx * m : 0.f;
      pw2 = (vy1 && vx0) ? ly * (1.f - lx) * m : 0.f;
      pw3 = (vy1 && vx1) ? ly * lx * m : 0.f;
      pp00 = fg + (size_t)(y0c * IMG + x0c) * 8;
      pp01 = fg + (size_t)(y0c * IMG + x1c) * 8;
      pp10 = fg + (size_t)(y1c * IMG + x0c) * 8;
      pp11 = fg + (size_t)(y1c * IMG + x1c) * 8;
    };

    float4 ga0, ga1, gb0, gb1, gc0, gc1, gd0, gd1;
    auto issue = [&]() {
      ga0 = *reinterpret_cast<const float4*>(pp00);
      ga1 = *reinterpret_cast<const float4*>(pp00 + 4);
      gb0 = *reinterpret_cast<const float4*>(pp01);
      gb1 = *reinterpret_cast<const float4*>(pp01 + 4);
      gc0 = *reinterpret_cast<const float4*>(pp10);
      gc1 = *reinterpret_cast<const float4*>(pp10 + 4);
      gd0 = *reinterpret_cast<const float4*>(pp11);
      gd1 = *reinterpret_cast<const float4*>(pp11 + 4);
    };

    params(0);
    issue();
#pragma unroll 1
    for (int k = 0; k < 9; ++k) {
      float w00 = pw0, w01 = pw1, w10 = pw2, w11 = pw3;
      float s[8];
      s[0] = w00 * ga0.x + w01 * gb0.x + w10 * gc0.x + w11 * gd0.x;
      s[1] = w00 * ga0.y + w01 * gb0.y + w10 * gc0.y + w11 * gd0.y;
      s[2] = w00 * ga0.z + w01 * gb0.z + w10 * gc0.z + w11 * gd0.z;
      s[3] = w00 * ga0.w + w01 * gb0.w + w10 * gc0.w + w11 * gd0.w;
      s[4] = w00 * ga1.x + w01 * gb1.x + w10 * gc1.x + w11 * gd1.x;
      s[5] = w00 * ga1.y + w01 * gb1.y + w10 * gc1.y + w11 * gd1.y;
      s[6] = w00 * ga1.z + w01 * gb1.z + w10 * gc1.z + w11 * gd1.z;
      s[7] = w00 * ga1.w + w01 * gb1.w + w10 * gc1.w + w11 * gd1.w;
      if (k < 8) { params(k + 1); issue(); }   // gathers overlap FMA block
      const float* wt = wT + (((size_t)g * 9 + k) << 9);  // 512 contiguous
#pragma unroll
      for (int c = 0; c < 8; ++c)
#pragma unroll
        for (int o = 0; o < 64; ++o)
          acc[o] = fmaf(wt[c * 64 + o], s[c], acc[o]);
    }
  }
  float* part = (blockIdx.y == 0) ? part0 : part1;
#pragma unroll
  for (int o = 0; o < 64; ++o)
    part[(size_t)o * NPIX + pix] = acc[o];
}

// ---------------------------------------------------------------------------
extern "C" void kernel_launch(void* const* d_in, const int* in_sizes, int n_in,
                              void* d_out, int out_size, void* d_ws, size_t ws_size,
                              hipStream_t stream)
{
  const float* feat[2]  = {(const float*)d_in[0], (const float*)d_in[1]};
  const float* extra[2] = {(const float*)d_in[2], (const float*)d_in[3]};
  const float* flow[2]  = {(const float*)d_in[4], (const float*)d_in[5]};
  const float* ow[2][4];
  const float* ob[2][4];
  for (int br = 0; br < 2; ++br)
    for (int j = 0; j < 4; ++j) {
      ow[br][j] = (const float*)d_in[6 + br * 8 + j * 2];
      ob[br][j] = (const float*)d_in[6 + br * 8 + j * 2 + 1];
    }
  const float* dcnw[2] = {(const float*)d_in[22], (const float*)d_in[24]};
  const float* dcnb[2] = {(const float*)d_in[23], (const float*)d_in[25]};
  const float* fusw = (const float*)d_in[26];
  const float* fusb = (const float*)d_in[27];

  float* ws = (float*)d_ws;
  float* t0 = ws;                        // 64 planes (conv buf / mdcn partial 0)
  float* t1 = ws + (size_t)64 * NPIX;    // 64 planes (conv buf / featG)
  float* t2 = ws + (size_t)128 * NPIX;   // 216 planes (o216)
  float* t3 = ws + (size_t)344 * NPIX;   // 64 planes (mdcn partial 1)
  float* wT = ws + (size_t)408 * NPIX;   // 36864 floats
  float* outp = (float*)d_out;

  dim3 blk(256);
  for (int br = 0; br < 2; ++br) {
    // offset network
    conv3x3_k<128, 1152, true,  false, false><<<dim3(256, 4),  blk, 0, stream>>>(
        extra[br], nullptr, nullptr, ow[br][0], ob[br][0], t0, 64);
    conv3x3_k<64, 576, true,  false, false><<<dim3(256, 4),  blk, 0, stream>>>(
        t0, nullptr, nullptr, ow[br][1], ob[br][1], t1, 64);
    conv3x3_k<64, 576, true,  false, false><<<dim3(256, 4),  blk, 0, stream>>>(
        t1, nullptr, nullptr, ow[br][2], ob[br][2], t0, 64);
    conv3x3_k<64, 576, false, false, false><<<dim3(256, 14), blk, 0, stream>>>(
        t0, nullptr, nullptr, ow[br][3], ob[br][3], t2, 216);
    // deformable conv (sample + partial GEMM, reduce folded into fusion conv)
    wtprep_k<<<dim3(144), blk, 0, stream>>>(dcnw[br], wT);
    featg_k<<<dim3(256), blk, 0, stream>>>(feat[br], t1);
    mdcn_sample_k<<<dim3(256, 2), blk, 0, stream>>>(t1, t2, flow[br], wT, t0, t3);
    // fusion conv on the cin-slice for this branch; staging sums partials+bias
    if (br == 0)
      conv3x3_k<64, 1152, false, false, true><<<dim3(256, 4), blk, 0, stream>>>(
          t0, t3, dcnb[0], fusw, fusb, outp, 64);
    else
      conv3x3_k<64, 1152, false, true,  true><<<dim3(256, 4), blk, 0, stream>>>(
          t0, t3, dcnb[1], fusw + 576, fusb, outp, 64);
  }
}

// Round 5
// 959.711 us; speedup vs baseline: 5.1387x; 5.1387x over previous
//
#include <hip/hip_runtime.h>
#include <cstddef>
#include <cstdint>

constexpr int IMG = 256;
constexpr int NPIX = 65536;
constexpr int PW = 258;                 // padded dim of HWC activation buffers
constexpr size_t PREC = (size_t)PW * PW;

typedef _Float16 h8 __attribute__((ext_vector_type(8)));
typedef float f32x4 __attribute__((ext_vector_type(4)));

// ---------------------------------------------------------------------------
// Zero pad records (rows 0,257; cols 0,257) of a padded-HWC f16 buffer.
// ---------------------------------------------------------------------------
template<int CIN>
__global__ __launch_bounds__(256) void zeropad_k(_Float16* __restrict__ buf)
{
  constexpr int Q = CIN / 8;
  int i = blockIdx.x * 256 + threadIdx.x;
  if (i >= 1028 * Q) return;
  int pr = i / Q, qi = i - pr * Q;
  int rec;
  if (pr < 258) rec = pr;                                   // row 0
  else if (pr < 516) rec = 257 * 258 + (pr - 258);          // row 257
  else { int j = pr - 516; rec = (1 + (j >> 1)) * 258 + ((j & 1) ? 257 : 0); }
  *reinterpret_cast<uint4*>(&buf[(size_t)rec * CIN + qi * 8]) = uint4{0, 0, 0, 0};
}

// ---------------------------------------------------------------------------
// fp32 CHW -> padded-HWC f16 (hi, and lo residual if TRIPLE).
// SUM: in = (f16)a + (f16)b + cb[c]  (mdcn partial reduce + dcn bias), hi only.
// ---------------------------------------------------------------------------
template<int CIN, bool SUM, bool TRIPLE>
__global__ __launch_bounds__(256) void prep_hwc_k(
    const float* __restrict__ in, const _Float16* __restrict__ a,
    const _Float16* __restrict__ b, const float* __restrict__ cb,
    _Float16* __restrict__ oHi, _Float16* __restrict__ oLo)
{
  int pix = blockIdx.x * 256 + threadIdx.x;
  int py = pix >> 8, px = pix & 255;
  size_t rec = ((size_t)(py + 1) * PW + px + 1) * CIN;
#pragma unroll
  for (int c0 = 0; c0 < CIN; c0 += 8) {
    _Float16 th[8], tl[8];
#pragma unroll
    for (int j = 0; j < 8; ++j) {
      float v;
      if (SUM)
        v = (float)a[(size_t)(c0 + j) * NPIX + pix] +
            (float)b[(size_t)(c0 + j) * NPIX + pix] + cb[c0 + j];
      else
        v = in[(size_t)(c0 + j) * NPIX + pix];
      th[j] = (_Float16)v;
      if (TRIPLE) tl[j] = (_Float16)(v - (float)th[j]);
    }
    *reinterpret_cast<uint4*>(&oHi[rec + c0]) = *reinterpret_cast<uint4*>(th);
    if (TRIPLE)
      *reinterpret_cast<uint4*>(&oLo[rec + c0]) = *reinterpret_cast<uint4*>(tl);
  }
}

// ---------------------------------------------------------------------------
// Conv weights OIHW fp32 -> f16 fragment-sliced (hi + optional lo residual):
// idx = ((t*KC + c)*NBF + fg)*64 + lane; lane holds B[k][n]: n = fg*16+(l&15),
// cin = c*32 + (l>>4)*8 + j.  Zero-fill couts >= nvalid.
// ---------------------------------------------------------------------------
__global__ __launch_bounds__(256) void wprep_k(
    const float* __restrict__ w, int cin_tot, int cin_off, int KC, int NBF,
    int nvalid, _Float16* __restrict__ oHi, _Float16* __restrict__ oLo)
{
  int idx = blockIdx.x * 256 + threadIdx.x;
  if (idx >= 9 * KC * NBF * 64) return;
  int l = idx & 63;
  int r = idx >> 6;
  int fg = r % NBF; r /= NBF;
  int c = r % KC;
  int t = r / KC;
  int n = fg * 16 + (l & 15);
  int cinb = c * 32 + (l >> 4) * 8;
  _Float16 vh[8], vl[8];
#pragma unroll
  for (int j = 0; j < 8; ++j) {
    float x = 0.f;
    if (n < nvalid) x = w[((size_t)n * cin_tot + cin_off + cinb + j) * 9 + t];
    vh[j] = (_Float16)x;
    vl[j] = (_Float16)(x - (float)vh[j]);
  }
  *reinterpret_cast<uint4*>(oHi + (size_t)idx * 8) = *reinterpret_cast<uint4*>(vh);
  if (oLo)
    *reinterpret_cast<uint4*>(oLo + (size_t)idx * 8) = *reinterpret_cast<uint4*>(vl);
}

// ---------------------------------------------------------------------------
// MFMA implicit-GEMM 3x3 conv over padded-HWC f16 (hi/lo split if TRIPLE:
// D = Ah*Bh + Al*Bh + Ah*Bl, residual ~2^-21).
// Block: 64 px x 64 couts, 4 waves; wave = 64 px x 16 couts (mf=4).
// A staged once in LDS (3 rows x 66 recs, 16B-slot rotation); B in registers
// (tap-lookahead global loads, L2-hot). No barriers in the K-loop.
// EPI 0: padded-HWC f16 hi+lo out, +bias +lrelu
// EPI 1: OT CHW out + bias (LDS transpose)
// EPI 2: float CHW accumulate (no bias)
// ---------------------------------------------------------------------------
template<int CIN, int EPI, bool TRIPLE, typename OT>
__global__ __launch_bounds__(256) void conv_mfma_k(
    const _Float16* __restrict__ actHi, const _Float16* __restrict__ actLo,
    const _Float16* __restrict__ wHi, const _Float16* __restrict__ wLo,
    const float* __restrict__ bias, OT* __restrict__ out,
    _Float16* __restrict__ outLo, int ncout, int NBF)
{
  constexpr int Q = CIN / 8;
  constexpr int KC = CIN / 32;
  constexpr int NREC = 198;            // 3 rows x 66 cols
  __shared__ __align__(16) _Float16 sAh[NREC * CIN];
  __shared__ __align__(16) _Float16 sAl[TRIPLE ? NREC * CIN : 8];

  const int tid = threadIdx.x;
  const int lane = tid & 63;
  const int wv = tid >> 6;
  const int y = blockIdx.x >> 2;
  const int x0 = (blockIdx.x & 3) << 6;
  const int n0 = blockIdx.y << 6;

  // ---- stage A (rows y..y+2 padded, cols x0..x0+65), 16B-slot rotation
  for (int i = tid; i < NREC * Q; i += 256) {
    int rec = i / Q, q = i - rec * Q;
    int seg = rec / 66, xr = rec - seg * 66;
    size_t g = ((size_t)(y + seg) * PW + x0 + xr) * CIN + q * 8;
    int slot = (q + rec) & (Q - 1);
    *reinterpret_cast<uint4*>(&sAh[rec * CIN + slot * 8]) =
        *reinterpret_cast<const uint4*>(&actHi[g]);
    if (TRIPLE)
      *reinterpret_cast<uint4*>(&sAl[rec * CIN + slot * 8]) =
          *reinterpret_cast<const uint4*>(&actLo[g]);
  }

  // ---- B register prefetch (per-wave 16-cout fragment)
  const int fgw = (n0 >> 4) + wv;
  auto bload = [&](int t, int c, const _Float16* wsrc) {
    return *reinterpret_cast<const h8*>(
        &wsrc[((((size_t)t * KC + c) * NBF + fgw) * 64 + lane) * 8]);
  };
  h8 Bn[KC][2];
#pragma unroll
  for (int c = 0; c < KC; ++c) {
    Bn[c][0] = bload(0, c, wHi);
    if (TRIPLE) Bn[c][1] = bload(0, c, wLo);
  }

  f32x4 acc[4];
#pragma unroll
  for (int a = 0; a < 4; ++a) acc[a] = f32x4{0.f, 0.f, 0.f, 0.f};
  __syncthreads();

  const int m = lane & 15, kq = lane >> 4;
#pragma unroll 1
  for (int t = 0; t < 9; ++t) {
    h8 Bc[KC][2];
#pragma unroll
    for (int c = 0; c < KC; ++c) {
      Bc[c][0] = Bn[c][0];
      if (TRIPLE) Bc[c][1] = Bn[c][1];
    }
    if (t < 8) {
#pragma unroll
      for (int c = 0; c < KC; ++c) {
        Bn[c][0] = bload(t + 1, c, wHi);
        if (TRIPLE) Bn[c][1] = bload(t + 1, c, wLo);
      }
    }
    const int lrb = (t / 3) * 66 + (t % 3) + m;
#pragma unroll
    for (int c = 0; c < KC; ++c) {
      const int q = c * 4 + kq;
#pragma unroll
      for (int mf = 0; mf < 4; ++mf) {
        int lr = lrb + mf * 16;
        int slot = (q + lr) & (Q - 1);
        h8 ah = *reinterpret_cast<const h8*>(&sAh[lr * CIN + slot * 8]);
        acc[mf] = __builtin_amdgcn_mfma_f32_16x16x32_f16(ah, Bc[c][0], acc[mf], 0, 0, 0);
        if (TRIPLE) {
          h8 al = *reinterpret_cast<const h8*>(&sAl[lr * CIN + slot * 8]);
          acc[mf] = __builtin_amdgcn_mfma_f32_16x16x32_f16(al, Bc[c][0], acc[mf], 0, 0, 0);
          acc[mf] = __builtin_amdgcn_mfma_f32_16x16x32_f16(ah, Bc[c][1], acc[mf], 0, 0, 0);
        }
      }
    }
  }

  if (EPI == 0) {
    const int ch = wv * 16 + m;
    const float bv = bias[ch];
#pragma unroll
    for (int mf = 0; mf < 4; ++mf)
#pragma unroll
      for (int r = 0; r < 4; ++r) {
        int p = mf * 16 + kq * 4 + r;
        float v = acc[mf][r] + bv;
        v = (v >= 0.f) ? v : 0.1f * v;
        _Float16 hi = (_Float16)v;
        size_t rec = ((size_t)(y + 1) * PW + x0 + p + 1) * 64;
        reinterpret_cast<_Float16*>(out)[rec + ch] = hi;
        outLo[rec + ch] = (_Float16)(v - (float)hi);
      }
  } else {
    __syncthreads();                   // all waves done reading sA
    float* sF = reinterpret_cast<float*>(sAh);   // [64 couts][68] scratch
#pragma unroll
    for (int mf = 0; mf < 4; ++mf)
#pragma unroll
      for (int r = 0; r < 4; ++r) {
        int ml = mf * 16 + kq * 4 + r;           // px 0..63
        int nl = wv * 16 + m;                    // cout 0..63
        float v = acc[mf][r];
        if (EPI == 1) v += (n0 + nl < ncout) ? bias[n0 + nl] : 0.f;
        sF[nl * 68 + ml] = v;
      }
    __syncthreads();
    for (int i = tid; i < 1024; i += 256) {
      int row = i >> 4, cx = (i & 15) * 4;
      int gc = n0 + row;
      if (gc < ncout) {
        f32x4 v = *reinterpret_cast<f32x4*>(&sF[row * 68 + cx]);
        size_t ob = (size_t)gc * NPIX + (size_t)y * IMG + x0 + cx;
        if (EPI == 2) {
          float* op = reinterpret_cast<float*>(out) + ob;
          op[0] += v[0]; op[1] += v[1]; op[2] += v[2]; op[3] += v[3];
        } else if (sizeof(OT) == 2) {
          _Float16 t4[4] = {(_Float16)v[0], (_Float16)v[1],
                            (_Float16)v[2], (_Float16)v[3]};
          *reinterpret_cast<uint2*>(reinterpret_cast<_Float16*>(out) + ob) =
              *reinterpret_cast<uint2*>(t4);
        } else {
          *reinterpret_cast<f32x4*>(reinterpret_cast<float*>(out) + ob) = v;
        }
      }
    }
  }
}

// ---------------------------------------------------------------------------
// feat fp32 CHW -> f16 per-group records featG[g][pix][8]
// ---------------------------------------------------------------------------
__global__ __launch_bounds__(256) void featg_k(
    const float* __restrict__ in, _Float16* __restrict__ out)
{
  int pix = blockIdx.x * 256 + threadIdx.x;
#pragma unroll
  for (int g = 0; g < 8; ++g) {
    _Float16 t[8];
#pragma unroll
    for (int c = 0; c < 8; ++c)
      t[c] = (_Float16)in[(size_t)(g * 8 + c) * NPIX + pix];
    *reinterpret_cast<uint4*>(&out[((size_t)g * NPIX + pix) * 8]) =
        *reinterpret_cast<uint4*>(t);
  }
}

// ---------------------------------------------------------------------------
// dcn weight transpose (fp32): wT[((g*9+k)*8 + c)*64 + o] = w[o*576+g*72+c*9+k]
// ---------------------------------------------------------------------------
__global__ __launch_bounds__(256) void wtprep_k(
    const float* __restrict__ w, float* __restrict__ wT)
{
  int i = blockIdx.x * 256 + threadIdx.x;   // 36864
  int o = i & 63;
  int r = i >> 6;
  int c = r & 7;
  int gk = r >> 3;
  int k = gk % 9;
  int g = gk / 9;
  wT[i] = w[(size_t)o * 576 + g * 72 + c * 9 + k];
}

// ---------------------------------------------------------------------------
// MDCN sample + partial GEMM, pipelined taps; fp32 math, f16 storage.
// blockIdx.y splits groups 0-3 / 4-7.
// ---------------------------------------------------------------------------
__global__ __launch_bounds__(256) void mdcn_sample_k(
    const _Float16* __restrict__ featG, const _Float16* __restrict__ o216,
    const float* __restrict__ flow, const float* __restrict__ wT,
    _Float16* __restrict__ part0, _Float16* __restrict__ part1)
{
  const int pix = blockIdx.x * 256 + threadIdx.x;
  const int h = pix >> 8, x = pix & 255;
  const float fy = flow[NPIX + pix];   // flow[:, ::-1]: even off-ch += flow[1]
  const float fx = flow[pix];

  float acc[64];
#pragma unroll
  for (int o = 0; o < 64; ++o) acc[o] = 0.f;

#pragma unroll 1
  for (int gg = 0; gg < 4; ++gg) {
    const int g = (blockIdx.y << 2) + gg;
    const _Float16* fg = featG + (size_t)g * NPIX * 8;

    float raw[27];
#pragma unroll
    for (int k = 0; k < 9; ++k) {
      raw[3 * k + 0] = (float)o216[(size_t)(g * 18 + 2 * k) * NPIX + pix];
      raw[3 * k + 1] = (float)o216[(size_t)(g * 18 + 2 * k + 1) * NPIX + pix];
      raw[3 * k + 2] = (float)o216[(size_t)(144 + g * 9 + k) * NPIX + pix];
    }

    float pw0, pw1, pw2, pw3;
    const _Float16 *pp00, *pp01, *pp10, *pp11;
    auto params = [&](int k) {
      float mm = 1.f / (1.f + __expf(-raw[3 * k + 2]));
      float pyf = (float)h + (float)(k / 3 - 1) + 10.f * tanhf(raw[3 * k]) + fy;
      float pxf = (float)x + (float)(k % 3 - 1) + 10.f * tanhf(raw[3 * k + 1]) + fx;
      float y0f = floorf(pyf), x0f = floorf(pxf);
      float ly = pyf - y0f, lx = pxf - x0f;
      int y0 = (int)y0f, x0i = (int)x0f;
      int y1 = y0 + 1, x1 = x0i + 1;
      bool vy0 = (unsigned)y0 < (unsigned)IMG, vy1 = (unsigned)y1 < (unsigned)IMG;
      bool vx0 = (unsigned)x0i < (unsigned)IMG, vx1 = (unsigned)x1 < (unsigned)IMG;
      int y0c = min(max(y0, 0), IMG - 1), y1c = min(max(y1, 0), IMG - 1);
      int x0c = min(max(x0i, 0), IMG - 1), x1c = min(max(x1, 0), IMG - 1);
      pw0 = (vy0 && vx0) ? (1.f - ly) * (1.f - lx) * mm : 0.f;
      pw1 = (vy0 && vx1) ? (1.f - ly) * lx * mm : 0.f;
      pw2 = (vy1 && vx0) ? ly * (1.f - lx) * mm : 0.f;
      pw3 = (vy1 && vx1) ? ly * lx * mm : 0.f;
      pp00 = fg + (size_t)(y0c * IMG + x0c) * 8;
      pp01 = fg + (size_t)(y0c * IMG + x1c) * 8;
      pp10 = fg + (size_t)(y1c * IMG + x0c) * 8;
      pp11 = fg + (size_t)(y1c * IMG + x1c) * 8;
    };

    h8 ga, gb, gc, gd;
    auto issue = [&]() {
      ga = *reinterpret_cast<const h8*>(pp00);
      gb = *reinterpret_cast<const h8*>(pp01);
      gc = *reinterpret_cast<const h8*>(pp10);
      gd = *reinterpret_cast<const h8*>(pp11);
    };

    params(0);
    issue();
#pragma unroll 1
    for (int k = 0; k < 9; ++k) {
      float w00 = pw0, w01 = pw1, w10 = pw2, w11 = pw3;
      float s[8];
#pragma unroll
      for (int j = 0; j < 8; ++j)
        s[j] = w00 * (float)ga[j] + w01 * (float)gb[j] +
               w10 * (float)gc[j] + w11 * (float)gd[j];
      if (k < 8) { params(k + 1); issue(); }
      const float* wt = wT + (((size_t)g * 9 + k) << 9);
#pragma unroll
      for (int c = 0; c < 8; ++c)
#pragma unroll
        for (int o = 0; o < 64; ++o)
          acc[o] = fmaf(wt[c * 64 + o], s[c], acc[o]);
    }
  }
  _Float16* part = (blockIdx.y == 0) ? part0 : part1;
#pragma unroll
  for (int o = 0; o < 64; ++o)
    part[(size_t)o * NPIX + pix] = (_Float16)acc[o];
}

// ---------------------------------------------------------------------------
extern "C" void kernel_launch(void* const* d_in, const int* in_sizes, int n_in,
                              void* d_out, int out_size, void* d_ws, size_t ws_size,
                              hipStream_t stream)
{
  const float* feat[2]  = {(const float*)d_in[0], (const float*)d_in[1]};
  const float* extra[2] = {(const float*)d_in[2], (const float*)d_in[3]};
  const float* flow[2]  = {(const float*)d_in[4], (const float*)d_in[5]};
  const float* ow[2][4];
  const float* ob[2][4];
  for (int br = 0; br < 2; ++br)
    for (int j = 0; j < 4; ++j) {
      ow[br][j] = (const float*)d_in[6 + br * 8 + j * 2];
      ob[br][j] = (const float*)d_in[6 + br * 8 + j * 2 + 1];
    }
  const float* dcnw[2] = {(const float*)d_in[22], (const float*)d_in[24]};
  const float* dcnb[2] = {(const float*)d_in[23], (const float*)d_in[25]};
  const float* fusw = (const float*)d_in[26];
  const float* fusb = (const float*)d_in[27];

  char* wsb = (char*)d_ws;
  size_t off = 0;
  auto alloc = [&](size_t bytes) {
    void* p = wsb + off;
    off += (bytes + 255) & ~(size_t)255;
    return p;
  };
  // actI hi+lo contiguous (34.1 MB); o216 f16 CHW (28.3 MB) aliases it.
  // Pads re-zeroed every branch, after o216 is dead.
  _Float16* actIhi = (_Float16*)alloc(PREC * 128 * 2);
  _Float16* actIlo = (_Float16*)alloc(PREC * 128 * 2);
  _Float16* o216   = actIhi;
  _Float16* actAhi = (_Float16*)alloc(PREC * 64 * 2);
  _Float16* actAlo = (_Float16*)alloc(PREC * 64 * 2);
  _Float16* actBhi = (_Float16*)alloc(PREC * 64 * 2);
  _Float16* actBlo = (_Float16*)alloc(PREC * 64 * 2);
  _Float16* featG  = actBlo;           // alias: actB dead after conv2
  _Float16* actF   = actBhi;           // alias: fusion input
  _Float16* p0 = (_Float16*)alloc((size_t)64 * NPIX * 2);
  _Float16* p1 = (_Float16*)alloc((size_t)64 * NPIX * 2);
  float* wT = (float*)alloc(36864 * 4);
  _Float16* wb0h = (_Float16*)alloc(147456); _Float16* wb0l = (_Float16*)alloc(147456);
  _Float16* wb1h = (_Float16*)alloc(73728);  _Float16* wb1l = (_Float16*)alloc(73728);
  _Float16* wb2h = (_Float16*)alloc(73728);  _Float16* wb2l = (_Float16*)alloc(73728);
  _Float16* wb3h = (_Float16*)alloc(294912); _Float16* wb3l = (_Float16*)alloc(294912);
  _Float16* wbFh = (_Float16*)alloc(73728);
  float* outp = (float*)d_out;

  dim3 blk(256);
  for (int br = 0; br < 2; ++br) {
    // re-zero all pads (o216/featG aliasing clobbers them; ws re-poisoned)
    zeropad_k<128><<<dim3(65), blk, 0, stream>>>(actIhi);
    zeropad_k<128><<<dim3(65), blk, 0, stream>>>(actIlo);
    zeropad_k<64><<<dim3(33), blk, 0, stream>>>(actAhi);
    zeropad_k<64><<<dim3(33), blk, 0, stream>>>(actAlo);
    zeropad_k<64><<<dim3(33), blk, 0, stream>>>(actBhi);
    zeropad_k<64><<<dim3(33), blk, 0, stream>>>(actBlo);

    // offset network (hi/lo split MFMA, near-fp32)
    prep_hwc_k<128, false, true><<<dim3(256), blk, 0, stream>>>(
        extra[br], nullptr, nullptr, nullptr, actIhi, actIlo);
    wprep_k<<<dim3(36), blk, 0, stream>>>(ow[br][0], 128, 0, 4, 4, 64, wb0h, wb0l);
    conv_mfma_k<128, 0, true, _Float16><<<dim3(1024, 1), blk, 0, stream>>>(
        actIhi, actIlo, wb0h, wb0l, ob[br][0], actAhi, actAlo, 64, 4);
    wprep_k<<<dim3(18), blk, 0, stream>>>(ow[br][1], 64, 0, 2, 4, 64, wb1h, wb1l);
    conv_mfma_k<64, 0, true, _Float16><<<dim3(1024, 1), blk, 0, stream>>>(
        actAhi, actAlo, wb1h, wb1l, ob[br][1], actBhi, actBlo, 64, 4);
    wprep_k<<<dim3(18), blk, 0, stream>>>(ow[br][2], 64, 0, 2, 4, 64, wb2h, wb2l);
    conv_mfma_k<64, 0, true, _Float16><<<dim3(1024, 1), blk, 0, stream>>>(
        actBhi, actBlo, wb2h, wb2l, ob[br][2], actAhi, actAlo, 64, 4);
    wprep_k<<<dim3(72), blk, 0, stream>>>(ow[br][3], 64, 0, 2, 16, 216, wb3h, wb3l);
    conv_mfma_k<64, 1, true, _Float16><<<dim3(1024, 4), blk, 0, stream>>>(
        actAhi, actAlo, wb3h, wb3l, ob[br][3], o216, nullptr, 216, 16);

    // deformable conv (fp32 math, f16 storage)
    wtprep_k<<<dim3(144), blk, 0, stream>>>(dcnw[br], wT);
    featg_k<<<dim3(256), blk, 0, stream>>>(feat[br], featG);
    mdcn_sample_k<<<dim3(256, 2), blk, 0, stream>>>(featG, o216, flow[br], wT, p0, p1);

    // fusion conv (partial reduce + dcn bias folded into prep; single f16)
    prep_hwc_k<64, true, false><<<dim3(256), blk, 0, stream>>>(
        nullptr, p0, p1, dcnb[br], actF, nullptr);
    wprep_k<<<dim3(18), blk, 0, stream>>>(fusw, 128, br * 64, 2, 4, 64, wbFh, nullptr);
    if (br == 0)
      conv_mfma_k<64, 1, false, float><<<dim3(1024, 1), blk, 0, stream>>>(
          actF, nullptr, wbFh, nullptr, fusb, outp, nullptr, 64, 4);
    else
      conv_mfma_k<64, 2, false, float><<<dim3(1024, 1), blk, 0, stream>>>(
          actF, nullptr, wbFh, nullptr, nullptr, outp, nullptr, 64, 4);
  }
}

// Round 6
// 657.055 us; speedup vs baseline: 7.5058x; 1.4606x over previous
//
#include <hip/hip_runtime.h>
#include <cstddef>
#include <cstdint>

constexpr int IMG = 256;
constexpr int NPIX = 65536;
constexpr int PW = 258;                 // padded dim of HWC activation buffers
constexpr size_t PREC = (size_t)PW * PW;

typedef _Float16 h8 __attribute__((ext_vector_type(8)));
typedef float f32x4 __attribute__((ext_vector_type(4)));

// ---------------------------------------------------------------------------
// Zero pad records (rows 0,257; cols 0,257) of a padded-HWC f16 buffer.
// ---------------------------------------------------------------------------
template<int CIN>
__device__ __forceinline__ void zero_pad_rec(int i, _Float16* buf)
{
  constexpr int Q = CIN / 8;
  if (i >= 1028 * Q) return;
  int pr = i / Q, qi = i - pr * Q;
  int rec;
  if (pr < 258) rec = pr;                                   // row 0
  else if (pr < 516) rec = 257 * 258 + (pr - 258);          // row 257
  else { int j = pr - 516; rec = (1 + (j >> 1)) * 258 + ((j & 1) ? 257 : 0); }
  *reinterpret_cast<uint4*>(&buf[(size_t)rec * CIN + qi * 8]) = uint4{0, 0, 0, 0};
}

template<int CIN>
__global__ __launch_bounds__(256) void zeropad_k(_Float16* __restrict__ buf)
{
  zero_pad_rec<CIN>(blockIdx.x * 256 + threadIdx.x, buf);
}

// ---------------------------------------------------------------------------
// fp32 CHW -> padded-HWC f16 (interior), pad-zeroing folded into extra blocks.
// ---------------------------------------------------------------------------
template<int CIN>
__global__ __launch_bounds__(256) void prep_hwc_k(
    const float* __restrict__ in, _Float16* __restrict__ out)
{
  int b = blockIdx.x;
  if (b >= 256) { zero_pad_rec<CIN>((b - 256) * 256 + threadIdx.x, out); return; }
  int pix = b * 256 + threadIdx.x;
  int py = pix >> 8, px = pix & 255;
  size_t rec = ((size_t)(py + 1) * PW + px + 1) * CIN;
#pragma unroll
  for (int c0 = 0; c0 < CIN; c0 += 8) {
    _Float16 t[8];
#pragma unroll
    for (int j = 0; j < 8; ++j)
      t[j] = (_Float16)in[(size_t)(c0 + j) * NPIX + pix];
    *reinterpret_cast<uint4*>(&out[rec + c0]) = *reinterpret_cast<uint4*>(t);
  }
}

// ---------------------------------------------------------------------------
// Fusion prep: actF = p0+p1+p2+p3 + dcn_bias, padded-HWC f16, pads folded.
// ---------------------------------------------------------------------------
__global__ __launch_bounds__(256) void prep_sum_k(
    const _Float16* __restrict__ p0, const _Float16* __restrict__ p1,
    const _Float16* __restrict__ p2, const _Float16* __restrict__ p3,
    const float* __restrict__ cb, _Float16* __restrict__ out)
{
  int b = blockIdx.x;
  if (b >= 256) { zero_pad_rec<64>((b - 256) * 256 + threadIdx.x, out); return; }
  int pix = b * 256 + threadIdx.x;
  int py = pix >> 8, px = pix & 255;
  size_t rec = ((size_t)(py + 1) * PW + px + 1) * 64;
#pragma unroll
  for (int c0 = 0; c0 < 64; c0 += 8) {
    _Float16 t[8];
#pragma unroll
    for (int j = 0; j < 8; ++j) {
      size_t gi = (size_t)(c0 + j) * NPIX + pix;
      t[j] = (_Float16)((float)p0[gi] + (float)p1[gi] + (float)p2[gi] +
                        (float)p3[gi] + cb[c0 + j]);
    }
    *reinterpret_cast<uint4*>(&out[rec + c0]) = *reinterpret_cast<uint4*>(t);
  }
}

// ---------------------------------------------------------------------------
// Weight fragment slicing (hi + optional f16 residual lo):
// dst idx = ((t*KC + c)*NBF + fg)*64 + lane, 8 f16; lane holds B[k][n]:
// n = fg*16 + (l&15), cin = c*32 + (l>>4)*8 + j. Zero-fill n >= nvalid.
// ---------------------------------------------------------------------------
__device__ __forceinline__ void wfrag(
    const float* __restrict__ w, int cin_tot, int cin_off, int KC, int NBF,
    int nvalid, int idx, _Float16* __restrict__ oHi, _Float16* __restrict__ oLo)
{
  int l = idx & 63;
  int r = idx >> 6;
  int fg = r % NBF; r /= NBF;
  int c = r % KC;
  int t = r / KC;
  int n = fg * 16 + (l & 15);
  int cinb = c * 32 + (l >> 4) * 8;
  _Float16 vh[8], vl[8];
#pragma unroll
  for (int j = 0; j < 8; ++j) {
    float x = 0.f;
    if (n < nvalid) x = w[((size_t)n * cin_tot + cin_off + cinb + j) * 9 + t];
    vh[j] = (_Float16)x;
    vl[j] = (_Float16)(x - (float)vh[j]);
  }
  *reinterpret_cast<uint4*>(oHi + (size_t)idx * 8) = *reinterpret_cast<uint4*>(vh);
  if (oLo)
    *reinterpret_cast<uint4*>(oLo + (size_t)idx * 8) = *reinterpret_cast<uint4*>(vl);
}

// One launch per branch preps all conv weight buffers + the dcn wT transpose.
__global__ __launch_bounds__(256) void wprep_all_k(
    const float* __restrict__ w0, const float* __restrict__ w1,
    const float* __restrict__ w2, const float* __restrict__ w3,
    const float* __restrict__ wf, int wf_cin_off, const float* __restrict__ dw,
    _Float16* b0h, _Float16* b0l, _Float16* b1h, _Float16* b1l,
    _Float16* b2h, _Float16* b2l, _Float16* b3h, _Float16* b3l,
    _Float16* bfh, float* __restrict__ wT)
{
  int idx = blockIdx.x * 256 + threadIdx.x;
  if (idx < 9216)       wfrag(w0, 128, 0, 4, 4, 64, idx, b0h, b0l);
  else if (idx < 13824) wfrag(w1, 64, 0, 2, 4, 64, idx - 9216, b1h, b1l);
  else if (idx < 18432) wfrag(w2, 64, 0, 2, 4, 64, idx - 13824, b2h, b2l);
  else if (idx < 36864) wfrag(w3, 64, 0, 2, 16, 216, idx - 18432, b3h, b3l);
  else if (idx < 41472) wfrag(wf, 128, wf_cin_off, 2, 4, 64, idx - 36864, bfh, nullptr);
  else if (idx < 78336) {
    int i = idx - 41472;                 // wT[((g*9+k)*8+c)*64+o] = dw[o,g,c,k]
    int o = i & 63;
    int r = i >> 6;
    int c = r & 7;
    int gk = r >> 3;
    int k = gk % 9;
    int g = gk / 9;
    wT[i] = dw[(size_t)o * 576 + g * 72 + c * 9 + k];
  }
}

// ---------------------------------------------------------------------------
// MFMA implicit-GEMM 3x3 conv over padded-HWC f16.
// DBL: weights hi/lo split (D = Ah*Bh + Ah*Bl); activations single f16.
// Block: 128 thr = 2 waves; 64 px x 64 couts; wave = 64px(mf4) x 32cout(nf2).
// A staged once in LDS (3 rows x 66 recs, 16B-slot rotation); B in registers
// (tap-lookahead global loads, L2-hot). No barriers in the K-loop.
// XCD row-band swizzle: XCD i handles image rows i*32..i*32+31.
// EPI 0: padded-HWC f16 out + bias + lrelu
// EPI 1: OT CHW out + bias (LDS transpose)
// EPI 2: float CHW accumulate (no bias)
// ---------------------------------------------------------------------------
template<int CIN, int EPI, bool DBL, typename OT>
__global__ __launch_bounds__(128) void conv_mfma_k(
    const _Float16* __restrict__ act, const _Float16* __restrict__ wHi,
    const _Float16* __restrict__ wLo, const float* __restrict__ bias,
    OT* __restrict__ out, int ncout, int NBF)
{
  constexpr int Q = CIN / 8;
  constexpr int KC = CIN / 32;
  constexpr int NT = DBL ? 2 : 1;
  constexpr int NREC = 198;            // 3 rows x 66 cols
  __shared__ __align__(16) _Float16 sA[NREC * CIN];

  const int tid = threadIdx.x;
  const int lane = tid & 63;
  const int wv = tid >> 6;
  const int b = blockIdx.x;
  const int inner = b >> 3;
  const int y = (b & 7) * 32 + (inner & 31);   // XCD row band
  const int x0 = (inner >> 5) << 6;
  const int n0 = blockIdx.y << 6;

  // ---- stage A (rows y..y+2 padded, cols x0..x0+65), 16B-slot rotation
  for (int i = tid; i < NREC * Q; i += 128) {
    int rec = i / Q, q = i - rec * Q;
    int seg = rec / 66, xr = rec - seg * 66;
    size_t g = ((size_t)(y + seg) * PW + x0 + xr) * CIN + q * 8;
    int slot = (q + rec) & (Q - 1);
    *reinterpret_cast<uint4*>(&sA[rec * CIN + slot * 8]) =
        *reinterpret_cast<const uint4*>(&act[g]);
  }

  // ---- B register prefetch: wave covers couts n0 + wv*32 .. +31 (2 frags)
  const int fgb = (n0 >> 4) + wv * 2;
  auto bload = [&](int t, int c, int nf, const _Float16* src) {
    return *reinterpret_cast<const h8*>(
        &src[((((size_t)t * KC + c) * NBF + fgb + nf) * 64 + lane) * 8]);
  };
  h8 Bn[KC][2][NT];
#pragma unroll
  for (int c = 0; c < KC; ++c)
#pragma unroll
    for (int nf = 0; nf < 2; ++nf) {
      Bn[c][nf][0] = bload(0, c, nf, wHi);
      if (DBL) Bn[c][nf][1] = bload(0, c, nf, wLo);
    }

  f32x4 acc[4][2];
#pragma unroll
  for (int a = 0; a < 4; ++a)
#pragma unroll
    for (int n = 0; n < 2; ++n) acc[a][n] = f32x4{0.f, 0.f, 0.f, 0.f};
  __syncthreads();

  const int m = lane & 15, kq = lane >> 4;
#pragma unroll 1
  for (int t = 0; t < 9; ++t) {
    h8 Bc[KC][2][NT];
#pragma unroll
    for (int c = 0; c < KC; ++c)
#pragma unroll
      for (int nf = 0; nf < 2; ++nf) {
        Bc[c][nf][0] = Bn[c][nf][0];
        if (DBL) Bc[c][nf][1] = Bn[c][nf][1];
      }
    if (t < 8) {
#pragma unroll
      for (int c = 0; c < KC; ++c)
#pragma unroll
        for (int nf = 0; nf < 2; ++nf) {
          Bn[c][nf][0] = bload(t + 1, c, nf, wHi);
          if (DBL) Bn[c][nf][1] = bload(t + 1, c, nf, wLo);
        }
    }
    const int lrb = (t / 3) * 66 + (t % 3) + m;
#pragma unroll
    for (int c = 0; c < KC; ++c) {
      const int q = c * 4 + kq;
#pragma unroll
      for (int mf = 0; mf < 4; ++mf) {
        int lr = lrb + mf * 16;
        int slot = (q + lr) & (Q - 1);
        h8 ah = *reinterpret_cast<const h8*>(&sA[lr * CIN + slot * 8]);
#pragma unroll
        for (int nf = 0; nf < 2; ++nf) {
          acc[mf][nf] = __builtin_amdgcn_mfma_f32_16x16x32_f16(
              ah, Bc[c][nf][0], acc[mf][nf], 0, 0, 0);
          if (DBL)
            acc[mf][nf] = __builtin_amdgcn_mfma_f32_16x16x32_f16(
                ah, Bc[c][nf][1], acc[mf][nf], 0, 0, 0);
        }
      }
    }
  }

  if (EPI == 0) {
#pragma unroll
    for (int nf = 0; nf < 2; ++nf) {
      const int ch = wv * 32 + nf * 16 + m;
      const float bv = bias[ch];
#pragma unroll
      for (int mf = 0; mf < 4; ++mf)
#pragma unroll
        for (int r = 0; r < 4; ++r) {
          int p = mf * 16 + kq * 4 + r;
          float v = acc[mf][nf][r] + bv;
          v = (v >= 0.f) ? v : 0.1f * v;
          reinterpret_cast<_Float16*>(out)[((size_t)(y + 1) * PW + x0 + p + 1) * 64 + ch] =
              (_Float16)v;
        }
    }
  } else {
    __syncthreads();                   // all waves done reading sA
    float* sF = reinterpret_cast<float*>(sA);   // [64 couts][68] scratch
#pragma unroll
    for (int mf = 0; mf < 4; ++mf)
#pragma unroll
      for (int nf = 0; nf < 2; ++nf) {
        int ml = mf * 16 + kq * 4;               // px 0..63 (4 at a time)
        int nl = wv * 32 + nf * 16 + m;          // cout 0..63
        f32x4 v = acc[mf][nf];
        if (EPI == 1) {
          float bv = (n0 + nl < ncout) ? bias[n0 + nl] : 0.f;
          v[0] += bv; v[1] += bv; v[2] += bv; v[3] += bv;
        }
        *reinterpret_cast<f32x4*>(&sF[nl * 68 + ml]) = v;
      }
    __syncthreads();
    for (int i = tid; i < 1024; i += 128) {
      int row = i >> 4, cx = (i & 15) * 4;
      int gc = n0 + row;
      if (gc < ncout) {
        f32x4 v = *reinterpret_cast<f32x4*>(&sF[row * 68 + cx]);
        size_t ob = (size_t)gc * NPIX + (size_t)y * IMG + x0 + cx;
        if (EPI == 2) {
          float* op = reinterpret_cast<float*>(out) + ob;
          op[0] += v[0]; op[1] += v[1]; op[2] += v[2]; op[3] += v[3];
        } else if (sizeof(OT) == 2) {
          _Float16 t4[4] = {(_Float16)v[0], (_Float16)v[1],
                            (_Float16)v[2], (_Float16)v[3]};
          *reinterpret_cast<uint2*>(reinterpret_cast<_Float16*>(out) + ob) =
              *reinterpret_cast<uint2*>(t4);
        } else {
          *reinterpret_cast<f32x4*>(reinterpret_cast<float*>(out) + ob) = v;
        }
      }
    }
  }
}

// ---------------------------------------------------------------------------
// feat fp32 CHW -> f16 per-group records featG[g][pix][8]
// ---------------------------------------------------------------------------
__global__ __launch_bounds__(256) void featg_k(
    const float* __restrict__ in, _Float16* __restrict__ out)
{
  int pix = blockIdx.x * 256 + threadIdx.x;
#pragma unroll
  for (int g = 0; g < 8; ++g) {
    _Float16 t[8];
#pragma unroll
    for (int c = 0; c < 8; ++c)
      t[c] = (_Float16)in[(size_t)(g * 8 + c) * NPIX + pix];
    *reinterpret_cast<uint4*>(&out[((size_t)g * NPIX + pix) * 8]) =
        *reinterpret_cast<uint4*>(t);
  }
}

// ---------------------------------------------------------------------------
// MDCN sample + partial GEMM; fp32 math, f16 storage. blockIdx.y in 0..3
// (2 groups each -> partial p[y]); XCD row-band swizzle on blockIdx.x.
// ---------------------------------------------------------------------------
__global__ __launch_bounds__(256) void mdcn_sample_k(
    const _Float16* __restrict__ featG, const _Float16* __restrict__ o216,
    const float* __restrict__ flow, const float* __restrict__ wT,
    _Float16* __restrict__ p0, _Float16* __restrict__ p1,
    _Float16* __restrict__ p2, _Float16* __restrict__ p3)
{
  const int b = blockIdx.x;
  const int row = (b & 7) * 32 + (b >> 3);      // XCD row band
  const int pix = row * 256 + threadIdx.x;
  const int h = row, x = threadIdx.x;
  const float fy = flow[NPIX + pix];   // flow[:, ::-1]: even off-ch += flow[1]
  const float fx = flow[pix];

  float acc[64];
#pragma unroll
  for (int o = 0; o < 64; ++o) acc[o] = 0.f;

#pragma unroll 1
  for (int gg = 0; gg < 2; ++gg) {
    const int g = (blockIdx.y << 1) + gg;
    const _Float16* fg = featG + (size_t)g * NPIX * 8;

    float raw[27];
#pragma unroll
    for (int k = 0; k < 9; ++k) {
      raw[3 * k + 0] = (float)o216[(size_t)(g * 18 + 2 * k) * NPIX + pix];
      raw[3 * k + 1] = (float)o216[(size_t)(g * 18 + 2 * k + 1) * NPIX + pix];
      raw[3 * k + 2] = (float)o216[(size_t)(144 + g * 9 + k) * NPIX + pix];
    }

    float pw0, pw1, pw2, pw3;
    const _Float16 *pp00, *pp01, *pp10, *pp11;
    auto params = [&](int k) {
      float mm = 1.f / (1.f + __expf(-raw[3 * k + 2]));
      float pyf = (float)h + (float)(k / 3 - 1) + 10.f * tanhf(raw[3 * k]) + fy;
      float pxf = (float)x + (float)(k % 3 - 1) + 10.f * tanhf(raw[3 * k + 1]) + fx;
      float y0f = floorf(pyf), x0f = floorf(pxf);
      float ly = pyf - y0f, lx = pxf - x0f;
      int y0 = (int)y0f, x0i = (int)x0f;
      int y1 = y0 + 1, x1 = x0i + 1;
      bool vy0 = (unsigned)y0 < (unsigned)IMG, vy1 = (unsigned)y1 < (unsigned)IMG;
      bool vx0 = (unsigned)x0i < (unsigned)IMG, vx1 = (unsigned)x1 < (unsigned)IMG;
      int y0c = min(max(y0, 0), IMG - 1), y1c = min(max(y1, 0), IMG - 1);
      int x0c = min(max(x0i, 0), IMG - 1), x1c = min(max(x1, 0), IMG - 1);
      pw0 = (vy0 && vx0) ? (1.f - ly) * (1.f - lx) * mm : 0.f;
      pw1 = (vy0 && vx1) ? (1.f - ly) * lx * mm : 0.f;
      pw2 = (vy1 && vx0) ? ly * (1.f - lx) * mm : 0.f;
      pw3 = (vy1 && vx1) ? ly * lx * mm : 0.f;
      pp00 = fg + (size_t)(y0c * IMG + x0c) * 8;
      pp01 = fg + (size_t)(y0c * IMG + x1c) * 8;
      pp10 = fg + (size_t)(y1c * IMG + x0c) * 8;
      pp11 = fg + (size_t)(y1c * IMG + x1c) * 8;
    };

    h8 ga, gb, gc, gd;
    auto issue = [&]() {
      ga = *reinterpret_cast<const h8*>(pp00);
      gb = *reinterpret_cast<const h8*>(pp01);
      gc = *reinterpret_cast<const h8*>(pp10);
      gd = *reinterpret_cast<const h8*>(pp11);
    };

    params(0);
    issue();
#pragma unroll 1
    for (int k = 0; k < 9; ++k) {
      float w00 = pw0, w01 = pw1, w10 = pw2, w11 = pw3;
      float s[8];
#pragma unroll
      for (int j = 0; j < 8; ++j)
        s[j] = w00 * (float)ga[j] + w01 * (float)gb[j] +
               w10 * (float)gc[j] + w11 * (float)gd[j];
      if (k < 8) { params(k + 1); issue(); }
      const float* wt = wT + (((size_t)g * 9 + k) << 9);
#pragma unroll
      for (int c = 0; c < 8; ++c)
#pragma unroll
        for (int o = 0; o < 64; ++o)
          acc[o] = fmaf(wt[c * 64 + o], s[c], acc[o]);
    }
  }
  _Float16* const parts[4] = {p0, p1, p2, p3};
  _Float16* part = parts[blockIdx.y];
#pragma unroll
  for (int o = 0; o < 64; ++o)
    part[(size_t)o * NPIX + pix] = (_Float16)acc[o];
}

// ---------------------------------------------------------------------------
extern "C" void kernel_launch(void* const* d_in, const int* in_sizes, int n_in,
                              void* d_out, int out_size, void* d_ws, size_t ws_size,
                              hipStream_t stream)
{
  const float* feat[2]  = {(const float*)d_in[0], (const float*)d_in[1]};
  const float* extra[2] = {(const float*)d_in[2], (const float*)d_in[3]};
  const float* flow[2]  = {(const float*)d_in[4], (const float*)d_in[5]};
  const float* ow[2][4];
  const float* ob[2][4];
  for (int br = 0; br < 2; ++br)
    for (int j = 0; j < 4; ++j) {
      ow[br][j] = (const float*)d_in[6 + br * 8 + j * 2];
      ob[br][j] = (const float*)d_in[6 + br * 8 + j * 2 + 1];
    }
  const float* dcnw[2] = {(const float*)d_in[22], (const float*)d_in[24]};
  const float* dcnb[2] = {(const float*)d_in[23], (const float*)d_in[25]};
  const float* fusw = (const float*)d_in[26];
  const float* fusb = (const float*)d_in[27];

  char* wsb = (char*)d_ws;
  size_t off = 0;
  auto alloc = [&](size_t bytes) {
    void* p = wsb + off;
    off += (bytes + 255) & ~(size_t)255;
    return p;
  };
  // no aliasing: pads of actA/actB survive the whole launch
  _Float16* actI = (_Float16*)alloc(PREC * 128 * 2);
  _Float16* actA = (_Float16*)alloc(PREC * 64 * 2);
  _Float16* actB = (_Float16*)alloc(PREC * 64 * 2);
  _Float16* actF = (_Float16*)alloc(PREC * 64 * 2);
  _Float16* o216 = (_Float16*)alloc((size_t)216 * NPIX * 2);
  _Float16* featG = (_Float16*)alloc((size_t)8 * NPIX * 8 * 2);
  _Float16* p0 = (_Float16*)alloc((size_t)64 * NPIX * 2);
  _Float16* p1 = (_Float16*)alloc((size_t)64 * NPIX * 2);
  _Float16* p2 = (_Float16*)alloc((size_t)64 * NPIX * 2);
  _Float16* p3 = (_Float16*)alloc((size_t)64 * NPIX * 2);
  float* wT = (float*)alloc(36864 * 4);
  _Float16* wb0h = (_Float16*)alloc(147456); _Float16* wb0l = (_Float16*)alloc(147456);
  _Float16* wb1h = (_Float16*)alloc(73728);  _Float16* wb1l = (_Float16*)alloc(73728);
  _Float16* wb2h = (_Float16*)alloc(73728);  _Float16* wb2l = (_Float16*)alloc(73728);
  _Float16* wb3h = (_Float16*)alloc(294912); _Float16* wb3l = (_Float16*)alloc(294912);
  _Float16* wbFh = (_Float16*)alloc(73728);
  float* outp = (float*)d_out;

  dim3 blk256(256), blk128(128);
  zeropad_k<64><<<dim3(33), blk256, 0, stream>>>(actA);
  zeropad_k<64><<<dim3(33), blk256, 0, stream>>>(actB);

  for (int br = 0; br < 2; ++br) {
    prep_hwc_k<128><<<dim3(321), blk256, 0, stream>>>(extra[br], actI);
    wprep_all_k<<<dim3(306), blk256, 0, stream>>>(
        ow[br][0], ow[br][1], ow[br][2], ow[br][3], fusw, br * 64, dcnw[br],
        wb0h, wb0l, wb1h, wb1l, wb2h, wb2l, wb3h, wb3l, wbFh, wT);

    // offset network (f16 MFMA, hi/lo-split weights)
    conv_mfma_k<128, 0, true, _Float16><<<dim3(1024, 1), blk128, 0, stream>>>(
        actI, wb0h, wb0l, ob[br][0], actA, 64, 4);
    conv_mfma_k<64, 0, true, _Float16><<<dim3(1024, 1), blk128, 0, stream>>>(
        actA, wb1h, wb1l, ob[br][1], actB, 64, 4);
    conv_mfma_k<64, 0, true, _Float16><<<dim3(1024, 1), blk128, 0, stream>>>(
        actB, wb2h, wb2l, ob[br][2], actA, 64, 4);
    conv_mfma_k<64, 1, true, _Float16><<<dim3(1024, 4), blk128, 0, stream>>>(
        actA, wb3h, wb3l, ob[br][3], o216, 216, 16);

    // deformable conv (fp32 math, f16 storage)
    featg_k<<<dim3(256), blk256, 0, stream>>>(feat[br], featG);
    mdcn_sample_k<<<dim3(256, 4), blk256, 0, stream>>>(
        featG, o216, flow[br], wT, p0, p1, p2, p3);

    // fusion conv (partial reduce + dcn bias folded into prep; single f16)
    prep_sum_k<<<dim3(289), blk256, 0, stream>>>(p0, p1, p2, p3, dcnb[br], actF);
    if (br == 0)
      conv_mfma_k<64, 1, false, float><<<dim3(1024, 1), blk128, 0, stream>>>(
          actF, wbFh, nullptr, fusb, outp, 64, 4);
    else
      conv_mfma_k<64, 2, false, float><<<dim3(1024, 1), blk128, 0, stream>>>(
          actF, wbFh, nullptr, nullptr, outp, 64, 4);
  }
}